// Round 1
// baseline (1382.697 us; speedup 1.0000x reference)
//
#include <hip/hip_runtime.h>
#include <math.h>

#define HF 64
#define LEAKY 0.2f

// ---------------- CSR build ----------------

__global__ void hist_kernel(const int* __restrict__ dst, int* __restrict__ cnt, int E) {
    int i = blockIdx.x * blockDim.x + threadIdx.x;
    int stride = gridDim.x * blockDim.x;
    for (; i < E; i += stride) atomicAdd(&cnt[dst[i]], 1);
}

__global__ void scan_kernel(const int* __restrict__ cnt, int* __restrict__ row_ptr,
                            int* __restrict__ cursor, int n) {
    __shared__ int sums[1024];
    int t = threadIdx.x;
    int chunk = (n + 1023) >> 10;
    int b0 = t * chunk;
    int b1 = min(b0 + chunk, n);
    int s = 0;
    for (int i = b0; i < b1; ++i) s += cnt[i];
    sums[t] = s;
    __syncthreads();
    for (int off = 1; off < 1024; off <<= 1) {
        int v = (t >= off) ? sums[t - off] : 0;
        __syncthreads();
        sums[t] += v;
        __syncthreads();
    }
    int run = (t == 0) ? 0 : sums[t - 1];
    for (int i = b0; i < b1; ++i) {
        int c = cnt[i];
        row_ptr[i] = run;
        cursor[i] = run;
        run += c;
    }
    if (t == 1023) row_ptr[n] = sums[1023];
}

__global__ void scatter_kernel(const int* __restrict__ src, const int* __restrict__ dst,
                               int* __restrict__ cursor, int* __restrict__ ssrc, int E) {
    int i = blockIdx.x * blockDim.x + threadIdx.x;
    int stride = gridDim.x * blockDim.x;
    for (; i < E; i += stride) {
        int p = atomicAdd(&cursor[dst[i]], 1);
        ssrc[p] = src[i];
    }
}

// ---------------- GEMM: H = X @ W, el = H a_l, er = H a_r ----------------

template <int FIN>
__global__ __launch_bounds__(256)
void gemm_kernel(const float* __restrict__ X, const float* __restrict__ W,
                 const float* __restrict__ al, const float* __restrict__ ar,
                 float* __restrict__ H, float* __restrict__ el, float* __restrict__ er,
                 int n) {
    __shared__ float Wl[FIN * HF];
    int t = threadIdx.x;
    for (int i = t; i < FIN * HF; i += 256) Wl[i] = W[i];
    __syncthreads();
    int wave = t >> 6, lane = t & 63;
    float alv = al[lane], arv = ar[lane];
    for (int row = blockIdx.x * 4 + wave; row < n; row += gridDim.x * 4) {
        const float* xr = X + (size_t)row * FIN;
        float x0 = xr[lane];
        float acc = 0.f;
#pragma unroll
        for (int k = 0; k < 64; ++k) acc = fmaf(__shfl(x0, k), Wl[k * HF + lane], acc);
        if (FIN == 128) {
            float x1 = xr[64 + lane];
#pragma unroll
            for (int k = 0; k < 64; ++k) acc = fmaf(__shfl(x1, k), Wl[(64 + k) * HF + lane], acc);
        }
        H[(size_t)row * HF + lane] = acc;
        float pl = acc * alv, pr = acc * arv;
#pragma unroll
        for (int off = 32; off; off >>= 1) {
            pl += __shfl_xor(pl, off);
            pr += __shfl_xor(pr, off);
        }
        if (lane == 0) { el[row] = pl; er[row] = pr; }
    }
}

// ---------------- Edge phase: softmax over incoming edges + aggregation ----------------

__global__ __launch_bounds__(256)
void edge_kernel(const int* __restrict__ row_ptr, const int* __restrict__ ssrc,
                 const float* __restrict__ el, const float* __restrict__ er,
                 const float* __restrict__ H, const float* __restrict__ b,
                 float* __restrict__ Y, int n) {
    int wave = threadIdx.x >> 6, lane = threadIdx.x & 63;
    float bv = b[lane];
    for (int node = blockIdx.x * 4 + wave; node < n; node += gridDim.x * 4) {
        int s0 = row_ptr[node], s1 = row_ptr[node + 1];
        float ern = er[node];
        // pass 1: max of leaky(e) over edges (lanes stride edges)
        float m = -INFINITY;
        for (int j = s0 + lane; j < s1; j += 64) {
            float e = el[ssrc[j]] + ern;
            e = e > 0.f ? e : LEAKY * e;
            m = fmaxf(m, e);
        }
#pragma unroll
        for (int off = 32; off; off >>= 1) m = fmaxf(m, __shfl_xor(m, off));
        // pass 2: accumulate p * h[src], p-sum; normalize at end
        float acc = 0.f, psum = 0.f;
        for (int j = s0; j < s1; ++j) {
            int s = ssrc[j];
            float e = el[s] + ern;
            e = e > 0.f ? e : LEAKY * e;
            float p = __expf(e - m);
            psum += p;
            acc = fmaf(p, H[(size_t)s * HF + lane], acc);
        }
        float o = (s1 > s0) ? acc / psum : 0.f;
        o += bv;
        Y[(size_t)node * HF + lane] = o > 0.f ? o : 0.f;
    }
}

// ---------------- launch ----------------

extern "C" void kernel_launch(void* const* d_in, const int* in_sizes, int n_in,
                              void* d_out, int out_size, void* d_ws, size_t ws_size,
                              hipStream_t stream) {
    const int N = in_sizes[0] / 128;
    const int E = in_sizes[1];

    const float* in_feat = (const float*)d_in[0];
    const int* src = (const int*)d_in[1];
    const int* dst = (const int*)d_in[2];
    const float* W1 = (const float*)d_in[3];
    const float* al1 = (const float*)d_in[4];
    const float* ar1 = (const float*)d_in[5];
    const float* b1 = (const float*)d_in[6];
    const float* W2 = (const float*)d_in[7];
    const float* al2 = (const float*)d_in[8];
    const float* ar2 = (const float*)d_in[9];
    const float* b2 = (const float*)d_in[10];
    const float* W3 = (const float*)d_in[11];
    const float* al3 = (const float*)d_in[12];
    const float* ar3 = (const float*)d_in[13];
    const float* b3 = (const float*)d_in[14];

    char* ws = (char*)d_ws;
    size_t off = 0;
    auto alloc = [&](size_t bytes) {
        void* p = ws + off;
        off += (bytes + 255) & ~(size_t)255;
        return p;
    };
    int* cnt = (int*)alloc((size_t)N * 4);
    int* row_ptr = (int*)alloc(((size_t)N + 1) * 4);
    int* cursor = (int*)alloc((size_t)N * 4);
    int* ssrc = (int*)alloc((size_t)E * 4);
    float* el = (float*)alloc((size_t)N * 4);
    float* er = (float*)alloc((size_t)N * 4);
    float* Hbuf = (float*)alloc((size_t)N * HF * 4);
    float* Ybuf = (float*)alloc((size_t)N * HF * 4);

    hipMemsetAsync(cnt, 0, (size_t)N * 4, stream);
    hist_kernel<<<2048, 256, 0, stream>>>(dst, cnt, E);
    scan_kernel<<<1, 1024, 0, stream>>>(cnt, row_ptr, cursor, N);
    scatter_kernel<<<2048, 256, 0, stream>>>(src, dst, cursor, ssrc, E);

    int gb = (N + 3) / 4;

    // layer 1
    gemm_kernel<128><<<gb, 256, 0, stream>>>(in_feat, W1, al1, ar1, Hbuf, el, er, N);
    edge_kernel<<<gb, 256, 0, stream>>>(row_ptr, ssrc, el, er, Hbuf, b1, Ybuf, N);
    // layer 2
    gemm_kernel<64><<<gb, 256, 0, stream>>>(Ybuf, W2, al2, ar2, Hbuf, el, er, N);
    edge_kernel<<<gb, 256, 0, stream>>>(row_ptr, ssrc, el, er, Hbuf, b2, Ybuf, N);
    // layer 3
    gemm_kernel<64><<<gb, 256, 0, stream>>>(Ybuf, W3, al3, ar3, Hbuf, el, er, N);
    edge_kernel<<<gb, 256, 0, stream>>>(row_ptr, ssrc, el, er, Hbuf, b3, (float*)d_out, N);
}